// Round 2
// baseline (635.117 us; speedup 1.0000x reference)
//
#include <hip/hip_runtime.h>

// row_attention_maxindex on MI355X — R1: fp16 (not bf16) for theta/phi/g/P.
// Soft-argmax (index output) amplifies QK^T logit quantization noise; fp16's
// 2 extra mantissa bits cut it 4x at zero MFMA cost (f16 MFMA = bf16 rate,
// identical fragment layout). proj (fp32 SIMD GEMM) -> flash attention
// (fp16 MFMA, online softmax, fused soft-argmax) -> up GEMM -> BN.

typedef unsigned short u16;
typedef unsigned int   u32;
typedef float        floatx4 __attribute__((ext_vector_type(4)));
typedef unsigned int uintx4  __attribute__((ext_vector_type(4)));
typedef unsigned int uintx2  __attribute__((ext_vector_type(2)));
typedef _Float16     half8   __attribute__((ext_vector_type(8)));

#define HW 4096
#define CB 256
#define RP 128
#define EPSF 1e-5f

static __device__ __forceinline__ u16 f2bf(float f) {
  u32 u = __float_as_uint(f);
  u32 r = u + 0x7FFFu + ((u >> 16) & 1u);   // RNE
  return (u16)(r >> 16);
}
static __device__ __forceinline__ float bf2f(u16 h) {
  return __uint_as_float(((u32)h) << 16);
}
static __device__ __forceinline__ u16 f2h(float f) {
  _Float16 h = (_Float16)f;                 // RNE
  return __builtin_bit_cast(u16, h);
}
static __device__ __forceinline__ half8 as_h8(uintx4 v) {
  return __builtin_bit_cast(half8, v);
}

union Pk8 { u16 u[8]; uintx4 v; };
union Pk4 { u16 u[4]; uintx2 v; };

// ---------------------------------------------------------------------------
// Projection: out[b,pos,r] (or transposed out[b,r,pos]) =
//   sum_c x[b,c,pos]*w[r,c] (+ pre[b,pos]/128 * w[r,256]) + bias[r] (+ addend[b,r,pos])
// Block: 64 pos x 128 r, 256 threads, thread = 4 pos x 8 r. Output fp16.
// ---------------------------------------------------------------------------
__global__ __launch_bounds__(256) void ra_proj(
    const float* __restrict__ x, const float* __restrict__ w,
    const float* __restrict__ bias, const float* __restrict__ addend,
    const float* __restrict__ pre, u16* __restrict__ outp,
    int wstride, int transposed)
{
  __shared__ float x_lds[32][68];
  __shared__ float w_lds[32][132];
  const int tid  = threadIdx.x;
  const int b    = blockIdx.x >> 6;
  const int pos0 = (blockIdx.x & 63) * 64;
  const int rt = tid & 15, pt = tid >> 4;

  float acc[4][8];
  #pragma unroll
  for (int i = 0; i < 4; i++)
    #pragma unroll
    for (int j = 0; j < 8; j++) acc[i][j] = 0.f;

  const int xc = tid >> 3, xp = (tid & 7) * 8;        // x staging: c row, pos offset
  const int wr_ = tid >> 1, wc_ = (tid & 1) * 16;     // w staging

  for (int cc = 0; cc < 8; ++cc) {
    {
      const float* xr = x + ((size_t)(b * CB + cc * 32 + xc)) * HW + pos0 + xp;
      floatx4 a0 = *(const floatx4*)xr;
      floatx4 a1 = *(const floatx4*)(xr + 4);
      *(floatx4*)&x_lds[xc][xp]     = a0;
      *(floatx4*)&x_lds[xc][xp + 4] = a1;
    }
    {
      const float* wp = w + (size_t)wr_ * wstride + cc * 32 + wc_;
      #pragma unroll
      for (int jj = 0; jj < 16; jj++) w_lds[wc_ + jj][wr_] = wp[jj];
    }
    __syncthreads();
    #pragma unroll 8
    for (int c = 0; c < 32; c++) {
      floatx4 xv = *(const floatx4*)&x_lds[c][pt * 4];
      floatx4 w0 = *(const floatx4*)&w_lds[c][rt * 8];
      floatx4 w1 = *(const floatx4*)&w_lds[c][rt * 8 + 4];
      #pragma unroll
      for (int i = 0; i < 4; i++) {
        acc[i][0] += xv[i] * w0[0]; acc[i][1] += xv[i] * w0[1];
        acc[i][2] += xv[i] * w0[2]; acc[i][3] += xv[i] * w0[3];
        acc[i][4] += xv[i] * w1[0]; acc[i][5] += xv[i] * w1[1];
        acc[i][6] += xv[i] * w1[2]; acc[i][7] += xv[i] * w1[3];
      }
    }
    __syncthreads();
  }

  if (pre) {  // extra channel 256: pre/128 * w[r][256]
    float wcol[8];
    #pragma unroll
    for (int j = 0; j < 8; j++) wcol[j] = w[(size_t)(rt * 8 + j) * wstride + 256];
    #pragma unroll
    for (int i = 0; i < 4; i++) {
      float pv = pre[(size_t)b * HW + pos0 + pt * 4 + i] * (1.f / 128.f);
      #pragma unroll
      for (int j = 0; j < 8; j++) acc[i][j] += pv * wcol[j];
    }
  }
  #pragma unroll
  for (int j = 0; j < 8; j++) {
    float bs = bias[rt * 8 + j];
    #pragma unroll
    for (int i = 0; i < 4; i++) acc[i][j] += bs;
  }
  if (addend) {  // addend[b][r][pos]
    #pragma unroll
    for (int j = 0; j < 8; j++) {
      floatx4 av = *(const floatx4*)(addend + (size_t)(b * RP + rt * 8 + j) * HW + pos0 + pt * 4);
      #pragma unroll
      for (int i = 0; i < 4; i++) acc[i][j] += av[i];
    }
  }

  if (!transposed) {  // out[b][pos][r]
    #pragma unroll
    for (int i = 0; i < 4; i++) {
      Pk8 pk;
      #pragma unroll
      for (int j = 0; j < 8; j++) pk.u[j] = f2h(acc[i][j]);
      *(uintx4*)(outp + (size_t)(b * HW + pos0 + pt * 4 + i) * RP + rt * 8) = pk.v;
    }
  } else {            // out[b][r][pos]
    #pragma unroll
    for (int j = 0; j < 8; j++) {
      Pk4 pk;
      #pragma unroll
      for (int i = 0; i < 4; i++) pk.u[i] = f2h(acc[i][j]);
      *(uintx2*)(outp + (size_t)(b * RP + rt * 8 + j) * HW + pos0 + pt * 4) = pk.v;
    }
  }
}

// ---------------------------------------------------------------------------
// Flash attention + soft-argmax.
// theta[b][q][r], phiT[b][k][r], gT[b][v][k] (all fp16). Block: b, 64 queries
// (4 waves x 16 q). K-tiles of 64 keys, double-buffered LDS, 1-iter prefetch.
// mfma_f32_16x16x32_f16:
//   A: lane holds A[m=lane&15][k=quad*8+j]; B: B[k=quad*8+j][n=lane&15]
//   C/D: D[row=quad*4+reg][col=lane&15]   (m89/m91-verified, dtype-independent)
// ---------------------------------------------------------------------------
__global__ __launch_bounds__(256) void ra_flash(
    const u16* __restrict__ theta, const u16* __restrict__ phiT,
    const u16* __restrict__ gT, u16* __restrict__ after,
    float* __restrict__ index_out)
{
  // phi tile: [rchunk8 cb(16)][k(64)][16B], cb stride 65 uint4 (1040 B, bank-padded)
  __shared__ uintx4 phi_lds[2][16 * 65];
  // g tile:  [kchunk8 kcb(8)][v(128)][16B], kcb stride 129 uint4 (2064 B)
  __shared__ uintx4 g_lds[2][8 * 129];
  // P round-trip, per-wave private: [q(16)][k(64)] fp16, row stride 72 u16 (144 B)
  __shared__ u16 P_lds[4][16 * 72];

  const int tid  = threadIdx.x;
  const int b    = blockIdx.x >> 6;
  const int q0   = (blockIdx.x & 63) * 64;
  const int wv   = tid >> 6;
  const int lane = tid & 63;
  const int ln16 = lane & 15;
  const int quad = lane >> 4;

  // theta A-fragments (held all kernel): 4 chunks of r (K=32 each)
  uintx4 aq[4];
  {
    const uintx4* tr = (const uintx4*)(theta + (size_t)(b * HW + q0 + wv * 16 + ln16) * RP);
    #pragma unroll
    for (int c = 0; c < 4; c++) aq[c] = tr[c * 4 + quad];
  }

  floatx4 accO[8];
  #pragma unroll
  for (int v = 0; v < 8; v++) accO[v] = (floatx4)0.0f;
  float m_r[4], l_r[4], aC[4];
  #pragma unroll
  for (int r = 0; r < 4; r++) { m_r[r] = -3.0e38f; l_r[r] = 0.f; aC[r] = 0.f; }

  const int sk  = tid >> 4, scb = tid & 15;  // phi staging
  const int gv_ = tid >> 3, gcb = tid & 7;   // g staging

  uintx4 sp[4], sg[4];
  #pragma unroll
  for (int i = 0; i < 4; i++) {
    sp[i] = *(const uintx4*)(phiT + (size_t)(b * HW + i * 16 + sk) * RP + scb * 8);
    sg[i] = *(const uintx4*)(gT + (size_t)(b * RP + i * 32 + gv_) * HW + gcb * 8);
  }

  #pragma unroll 1
  for (int j = 0; j < 64; j++) {
    const int buf = j & 1;
    #pragma unroll
    for (int i = 0; i < 4; i++) {
      phi_lds[buf][scb * 65 + i * 16 + sk] = sp[i];
      g_lds[buf][gcb * 129 + i * 32 + gv_] = sg[i];
    }
    if (j < 63) {  // prefetch next tile into regs (latency hidden by compute)
      const int k0n = (j + 1) * 64;
      #pragma unroll
      for (int i = 0; i < 4; i++) {
        sp[i] = *(const uintx4*)(phiT + (size_t)(b * HW + k0n + i * 16 + sk) * RP + scb * 8);
        sg[i] = *(const uintx4*)(gT + (size_t)(b * RP + i * 32 + gv_) * HW + k0n + gcb * 8);
      }
    }
    __syncthreads();  // barrier A: tiles visible; also orders P read(j-1) vs write(j)

    // S[16q x 64k] = theta . phiT  (4 n-subtiles x 4 r-chunks)
    floatx4 sf[4];
    #pragma unroll
    for (int s = 0; s < 4; s++) sf[s] = (floatx4)0.0f;
    #pragma unroll
    for (int c = 0; c < 4; c++) {
      half8 a = as_h8(aq[c]);
      #pragma unroll
      for (int s = 0; s < 4; s++) {
        uintx4 bp = phi_lds[buf][(c * 4 + quad) * 65 + s * 16 + ln16];
        sf[s] = __builtin_amdgcn_mfma_f32_16x16x32_f16(a, as_h8(bp), sf[s], 0, 0, 0);
      }
    }

    // online softmax + col accumulation; write P (fp16) for A-operand re-read
    const float colbase = (float)((j * 64) & 127) + (float)ln16;
    #pragma unroll
    for (int r = 0; r < 4; r++) {
      float mx = fmaxf(fmaxf(sf[0][r], sf[1][r]), fmaxf(sf[2][r], sf[3][r]));
      mx = fmaxf(mx, __shfl_xor(mx, 1));
      mx = fmaxf(mx, __shfl_xor(mx, 2));
      mx = fmaxf(mx, __shfl_xor(mx, 4));
      mx = fmaxf(mx, __shfl_xor(mx, 8));
      const float mnew  = fmaxf(m_r[r], mx);
      const float alpha = __expf(m_r[r] - mnew);
      m_r[r] = mnew;
      float p0 = __expf(sf[0][r] - mnew);
      float p1 = __expf(sf[1][r] - mnew);
      float p2 = __expf(sf[2][r] - mnew);
      float p3 = __expf(sf[3][r] - mnew);
      float ps = p0 + p1 + p2 + p3;
      float pc = p0 * colbase + p1 * (colbase + 16.f) + p2 * (colbase + 32.f) + p3 * (colbase + 48.f);
      ps += __shfl_xor(ps, 1); ps += __shfl_xor(ps, 2);
      ps += __shfl_xor(ps, 4); ps += __shfl_xor(ps, 8);
      pc += __shfl_xor(pc, 1); pc += __shfl_xor(pc, 2);
      pc += __shfl_xor(pc, 4); pc += __shfl_xor(pc, 8);
      l_r[r] = l_r[r] * alpha + ps;
      aC[r]  = aC[r]  * alpha + pc;
      #pragma unroll
      for (int v = 0; v < 8; v++) accO[v][r] *= alpha;
      const int qrow = quad * 4 + r;
      P_lds[wv][qrow * 72 +      ln16] = f2h(p0);
      P_lds[wv][qrow * 72 + 16 + ln16] = f2h(p1);
      P_lds[wv][qrow * 72 + 32 + ln16] = f2h(p2);
      P_lds[wv][qrow * 72 + 48 + ln16] = f2h(p3);
    }
    __syncthreads();  // barrier B: P C-layout -> A-layout visible

    half8 pa0 = as_h8(*(const uintx4*)&P_lds[wv][ln16 * 72 + quad * 8]);
    half8 pa1 = as_h8(*(const uintx4*)&P_lds[wv][ln16 * 72 + 32 + quad * 8]);
    #pragma unroll
    for (int v = 0; v < 8; v++) {
      uintx4 bg0 = g_lds[buf][quad * 129 + v * 16 + ln16];
      uintx4 bg1 = g_lds[buf][(4 + quad) * 129 + v * 16 + ln16];
      accO[v] = __builtin_amdgcn_mfma_f32_16x16x32_f16(pa0, as_h8(bg0), accO[v], 0, 0, 0);
      accO[v] = __builtin_amdgcn_mfma_f32_16x16x32_f16(pa1, as_h8(bg1), accO[v], 0, 0, 0);
    }
  }

  #pragma unroll
  for (int r = 0; r < 4; r++) {
    const float inv = 1.0f / l_r[r];
    const int q = q0 + wv * 16 + quad * 4 + r;
    u16* arow = after + (size_t)(b * HW + q) * RP;
    #pragma unroll
    for (int v = 0; v < 8; v++) arow[v * 16 + ln16] = f2bf(accO[v][r] * inv);
    if (ln16 == 0) index_out[b * HW + q] = (float)(q & 127) - aC[r] * inv;
  }
}

// ---------------------------------------------------------------------------
// Up-projection: y[b,co,pos] = sum_r after[b,pos,r]*up_w[co,r] + up_b[co] (bf16 out)
// Block: 64 pos x 128 co (hc selects which half of 256 co).
// ---------------------------------------------------------------------------
__global__ __launch_bounds__(256) void ra_up(
    const u16* __restrict__ after, const float* __restrict__ w,
    const float* __restrict__ bias, u16* __restrict__ y)
{
  __shared__ float x_lds[32][68];   // [r][pos]
  __shared__ float w_lds[32][132];  // [r][co]
  const int tid  = threadIdx.x;
  const int bx   = blockIdx.x;
  const int b    = bx >> 7;
  const int pos0 = ((bx >> 1) & 63) * 64;
  const int hc   = bx & 1;
  const int rt = tid & 15, pt = tid >> 4;

  float acc[4][8];
  #pragma unroll
  for (int i = 0; i < 4; i++)
    #pragma unroll
    for (int j = 0; j < 8; j++) acc[i][j] = 0.f;

  const int apos = tid >> 2, ars = (tid & 3) * 8;
  const int wr_ = tid >> 1, wc_ = (tid & 1) * 16;

  for (int cc = 0; cc < 4; ++cc) {
    {
      const u16* ar = after + (size_t)(b * HW + pos0 + apos) * RP + cc * 32 + ars;
      uintx4 raw = *(const uintx4*)ar;
      #pragma unroll
      for (int k = 0; k < 4; k++) {
        u32 wd = raw[k];
        x_lds[ars + 2 * k][apos]     = bf2f((u16)(wd & 0xffffu));
        x_lds[ars + 2 * k + 1][apos] = bf2f((u16)(wd >> 16));
      }
    }
    {
      const float* wp = w + (size_t)(hc * 128 + wr_) * RP + cc * 32 + wc_;
      #pragma unroll
      for (int jj = 0; jj < 16; jj++) w_lds[wc_ + jj][wr_] = wp[jj];
    }
    __syncthreads();
    #pragma unroll 8
    for (int c = 0; c < 32; c++) {
      floatx4 xv = *(const floatx4*)&x_lds[c][pt * 4];
      floatx4 w0 = *(const floatx4*)&w_lds[c][rt * 8];
      floatx4 w1 = *(const floatx4*)&w_lds[c][rt * 8 + 4];
      #pragma unroll
      for (int i = 0; i < 4; i++) {
        acc[i][0] += xv[i] * w0[0]; acc[i][1] += xv[i] * w0[1];
        acc[i][2] += xv[i] * w0[2]; acc[i][3] += xv[i] * w0[3];
        acc[i][4] += xv[i] * w1[0]; acc[i][5] += xv[i] * w1[1];
        acc[i][6] += xv[i] * w1[2]; acc[i][7] += xv[i] * w1[3];
      }
    }
    __syncthreads();
  }

  #pragma unroll
  for (int j = 0; j < 8; j++) {
    const int co = hc * 128 + rt * 8 + j;
    const float bs = bias[co];
    Pk4 pk;
    #pragma unroll
    for (int i = 0; i < 4; i++) pk.u[i] = f2bf(acc[i][j] + bs);
    *(uintx2*)(y + (size_t)(b * CB + co) * HW + pos0 + pt * 4) = pk.v;
  }
}

// ---------------------------------------------------------------------------
// Per-channel batch stats over (B, HW): mean and rstd.
// ---------------------------------------------------------------------------
__global__ __launch_bounds__(256) void ra_stats(const u16* __restrict__ y,
                                                float* __restrict__ stats)
{
  const int c = blockIdx.x;
  const int tid = threadIdx.x;
  float s = 0.f, sq = 0.f;
  for (int b = 0; b < 4; b++) {
    const uintx4* row = (const uintx4*)(y + (size_t)(b * CB + c) * HW);
    #pragma unroll
    for (int t = 0; t < 2; t++) {
      uintx4 rv = row[tid + t * 256];
      #pragma unroll
      for (int k = 0; k < 4; k++) {
        float a0 = bf2f((u16)(rv[k] & 0xffffu));
        float a1 = bf2f((u16)(rv[k] >> 16));
        s += a0 + a1; sq += a0 * a0 + a1 * a1;
      }
    }
  }
  #pragma unroll
  for (int m = 1; m < 64; m <<= 1) { s += __shfl_xor(s, m); sq += __shfl_xor(sq, m); }
  __shared__ float red[8];
  const int wv = tid >> 6;
  if ((tid & 63) == 0) { red[wv * 2] = s; red[wv * 2 + 1] = sq; }
  __syncthreads();
  if (tid == 0) {
    s  = red[0] + red[2] + red[4] + red[6];
    sq = red[1] + red[3] + red[5] + red[7];
    const float mean = s * (1.f / 16384.f);
    const float var  = sq * (1.f / 16384.f) - mean * mean;
    stats[2 * c]     = mean;
    stats[2 * c + 1] = rsqrtf(var + EPSF);
  }
}

// ---------------------------------------------------------------------------
// out = x + gamma*(y - mean)*rstd + beta  (elementwise, float4)
// ---------------------------------------------------------------------------
__global__ __launch_bounds__(256) void ra_fin(
    const float* __restrict__ x, const u16* __restrict__ y,
    const float* __restrict__ stats, const float* __restrict__ gamma,
    const float* __restrict__ beta, float* __restrict__ out)
{
  const size_t e = (size_t)blockIdx.x * 256 + threadIdx.x;  // float4 index
  const int c = (int)((e >> 10) & 255);
  const float mean = stats[2 * c], rstd = stats[2 * c + 1];
  const float ga = gamma[c], be = beta[c];
  floatx4 xv = ((const floatx4*)x)[e];
  uintx2 yv = ((const uintx2*)y)[e];
  float f0 = bf2f((u16)(yv[0] & 0xffffu));
  float f1 = bf2f((u16)(yv[0] >> 16));
  float f2 = bf2f((u16)(yv[1] & 0xffffu));
  float f3 = bf2f((u16)(yv[1] >> 16));
  floatx4 o;
  o[0] = xv[0] + ga * ((f0 - mean) * rstd) + be;
  o[1] = xv[1] + ga * ((f1 - mean) * rstd) + be;
  o[2] = xv[2] + ga * ((f2 - mean) * rstd) + be;
  o[3] = xv[3] + ga * ((f3 - mean) * rstd) + be;
  ((floatx4*)out)[e] = o;
}

// ---------------------------------------------------------------------------
extern "C" void kernel_launch(void* const* d_in, const int* in_sizes, int n_in,
                              void* d_out, int out_size, void* d_ws, size_t ws_size,
                              hipStream_t stream)
{
  const float* left    = (const float*)d_in[0];
  const float* right   = (const float*)d_in[1];
  const float* pre_l   = (const float*)d_in[2];
  const float* pre_r   = (const float*)d_in[3];
  const float* query_l = (const float*)d_in[4];
  const float* key_l   = (const float*)d_in[5];
  const float* query_r = (const float*)d_in[6];
  const float* key_r   = (const float*)d_in[7];
  const float* theta_w = (const float*)d_in[8];
  const float* theta_b = (const float*)d_in[9];
  const float* phi_w   = (const float*)d_in[10];
  const float* phi_b   = (const float*)d_in[11];
  const float* g_w     = (const float*)d_in[12];
  const float* g_b     = (const float*)d_in[13];
  const float* up_w    = (const float*)d_in[14];
  const float* up_b    = (const float*)d_in[15];
  const float* bn_g    = (const float*)d_in[16];
  const float* bn_b    = (const float*)d_in[17];
  float* out = (float*)d_out;

  char* ws = (char*)d_ws;
  const size_t SZ = (size_t)4 * HW * RP * 2;  // 4 MiB (fp16 [4][4096][128])
  u16* thetaL = (u16*)(ws);
  u16* phiTL  = (u16*)(ws + 1 * SZ);
  u16* gTL    = (u16*)(ws + 2 * SZ);
  u16* thetaR = (u16*)(ws + 3 * SZ);
  u16* phiTR  = (u16*)(ws + 4 * SZ);
  u16* gTR    = (u16*)(ws + 5 * SZ);
  u16* afterL = (u16*)(ws + 6 * SZ);
  u16* afterR = (u16*)(ws + 7 * SZ);
  u16* yL     = (u16*)(ws + 8 * SZ);    // 8 MiB
  u16* yR     = (u16*)(ws + 10 * SZ);   // 8 MiB
  float* stL  = (float*)(ws + 12 * SZ);
  float* stR  = (float*)(ws + 12 * SZ + 4096);

  dim3 blk(256);
  // side L: x_q=left, x_kv=right, query_l, key_r; side R mirrored.
  ra_proj<<<256, blk, 0, stream>>>(left,  theta_w, theta_b, query_l, pre_l,  thetaL, 257, 0);
  ra_proj<<<256, blk, 0, stream>>>(right, phi_w,   phi_b,   key_r,   nullptr, phiTL, 256, 0);
  ra_proj<<<256, blk, 0, stream>>>(right, g_w,     g_b,     nullptr, nullptr, gTL,   256, 1);
  ra_proj<<<256, blk, 0, stream>>>(right, theta_w, theta_b, query_r, pre_r,  thetaR, 257, 0);
  ra_proj<<<256, blk, 0, stream>>>(left,  phi_w,   phi_b,   key_l,   nullptr, phiTR, 256, 0);
  ra_proj<<<256, blk, 0, stream>>>(left,  g_w,     g_b,     nullptr, nullptr, gTR,   256, 1);

  ra_flash<<<256, blk, 0, stream>>>(thetaL, phiTL, gTL, afterL, out + 8388608);
  ra_flash<<<256, blk, 0, stream>>>(thetaR, phiTR, gTR, afterR, out + 8404992);

  ra_up<<<512, blk, 0, stream>>>(afterL, up_w, up_b, yL);
  ra_up<<<512, blk, 0, stream>>>(afterR, up_w, up_b, yR);

  ra_stats<<<256, blk, 0, stream>>>(yL, stL);
  ra_stats<<<256, blk, 0, stream>>>(yR, stR);

  ra_fin<<<4096, blk, 0, stream>>>(left,  yL, stL, bn_g, bn_b, out);
  ra_fin<<<4096, blk, 0, stream>>>(right, yR, stR, bn_g, bn_b, out + 4194304);

  (void)in_sizes; (void)n_in; (void)out_size; (void)ws_size;
}

// Round 3
// 550.408 us; speedup vs baseline: 1.1539x; 1.1539x over previous
//
#include <hip/hip_runtime.h>

// row_attention_maxindex on MI355X — R2: split-K=2 flash-decoding.
// R1 counters: Occupancy 11% (1 block/CU), MfmaUtil 8.4% — barrier-lockstep
// latency-bound. 512 blocks -> 2 independent blocks/CU so one block's softmax
// VALU overlaps the other's MFMA (m114 co-scheduling). Partials (accO fp16,
// m/l/aC fp32) + combine kernel. P_lds stride 72->76 (kills 4-way ds_write_b16
// bank conflicts: 38 dwords = 6 mod 32).

typedef unsigned short u16;
typedef unsigned int   u32;
typedef float        floatx4 __attribute__((ext_vector_type(4)));
typedef unsigned int uintx4  __attribute__((ext_vector_type(4)));
typedef unsigned int uintx2  __attribute__((ext_vector_type(2)));
typedef _Float16     half8   __attribute__((ext_vector_type(8)));

#define HW 4096
#define CB 256
#define RP 128
#define EPSF 1e-5f

static __device__ __forceinline__ u16 f2bf(float f) {
  u32 u = __float_as_uint(f);
  u32 r = u + 0x7FFFu + ((u >> 16) & 1u);   // RNE
  return (u16)(r >> 16);
}
static __device__ __forceinline__ float bf2f(u16 h) {
  return __uint_as_float(((u32)h) << 16);
}
static __device__ __forceinline__ u16 f2h(float f) {
  _Float16 h = (_Float16)f;                 // RNE
  return __builtin_bit_cast(u16, h);
}
static __device__ __forceinline__ float h2f(u16 h) {
  return (float)__builtin_bit_cast(_Float16, h);
}
static __device__ __forceinline__ half8 as_h8(uintx4 v) {
  return __builtin_bit_cast(half8, v);
}

union Pk8 { u16 u[8]; uintx4 v; };
union Pk4 { u16 u[4]; uintx2 v; };

// ---------------------------------------------------------------------------
// Projection: out[b,pos,r] (or transposed out[b,r,pos]) =
//   sum_c x[b,c,pos]*w[r,c] (+ pre[b,pos]/128 * w[r,256]) + bias[r] (+ addend[b,r,pos])
// Block: 64 pos x 128 r, 256 threads, thread = 4 pos x 8 r. Output fp16.
// ---------------------------------------------------------------------------
__global__ __launch_bounds__(256) void ra_proj(
    const float* __restrict__ x, const float* __restrict__ w,
    const float* __restrict__ bias, const float* __restrict__ addend,
    const float* __restrict__ pre, u16* __restrict__ outp,
    int wstride, int transposed)
{
  __shared__ float x_lds[32][68];
  __shared__ float w_lds[32][132];
  const int tid  = threadIdx.x;
  const int b    = blockIdx.x >> 6;
  const int pos0 = (blockIdx.x & 63) * 64;
  const int rt = tid & 15, pt = tid >> 4;

  float acc[4][8];
  #pragma unroll
  for (int i = 0; i < 4; i++)
    #pragma unroll
    for (int j = 0; j < 8; j++) acc[i][j] = 0.f;

  const int xc = tid >> 3, xp = (tid & 7) * 8;        // x staging: c row, pos offset
  const int wr_ = tid >> 1, wc_ = (tid & 1) * 16;     // w staging

  for (int cc = 0; cc < 8; ++cc) {
    {
      const float* xr = x + ((size_t)(b * CB + cc * 32 + xc)) * HW + pos0 + xp;
      floatx4 a0 = *(const floatx4*)xr;
      floatx4 a1 = *(const floatx4*)(xr + 4);
      *(floatx4*)&x_lds[xc][xp]     = a0;
      *(floatx4*)&x_lds[xc][xp + 4] = a1;
    }
    {
      const float* wp = w + (size_t)wr_ * wstride + cc * 32 + wc_;
      #pragma unroll
      for (int jj = 0; jj < 16; jj++) w_lds[wc_ + jj][wr_] = wp[jj];
    }
    __syncthreads();
    #pragma unroll 8
    for (int c = 0; c < 32; c++) {
      floatx4 xv = *(const floatx4*)&x_lds[c][pt * 4];
      floatx4 w0 = *(const floatx4*)&w_lds[c][rt * 8];
      floatx4 w1 = *(const floatx4*)&w_lds[c][rt * 8 + 4];
      #pragma unroll
      for (int i = 0; i < 4; i++) {
        acc[i][0] += xv[i] * w0[0]; acc[i][1] += xv[i] * w0[1];
        acc[i][2] += xv[i] * w0[2]; acc[i][3] += xv[i] * w0[3];
        acc[i][4] += xv[i] * w1[0]; acc[i][5] += xv[i] * w1[1];
        acc[i][6] += xv[i] * w1[2]; acc[i][7] += xv[i] * w1[3];
      }
    }
    __syncthreads();
  }

  if (pre) {  // extra channel 256: pre/128 * w[r][256]
    float wcol[8];
    #pragma unroll
    for (int j = 0; j < 8; j++) wcol[j] = w[(size_t)(rt * 8 + j) * wstride + 256];
    #pragma unroll
    for (int i = 0; i < 4; i++) {
      float pv = pre[(size_t)b * HW + pos0 + pt * 4 + i] * (1.f / 128.f);
      #pragma unroll
      for (int j = 0; j < 8; j++) acc[i][j] += pv * wcol[j];
    }
  }
  #pragma unroll
  for (int j = 0; j < 8; j++) {
    float bs = bias[rt * 8 + j];
    #pragma unroll
    for (int i = 0; i < 4; i++) acc[i][j] += bs;
  }
  if (addend) {  // addend[b][r][pos]
    #pragma unroll
    for (int j = 0; j < 8; j++) {
      floatx4 av = *(const floatx4*)(addend + (size_t)(b * RP + rt * 8 + j) * HW + pos0 + pt * 4);
      #pragma unroll
      for (int i = 0; i < 4; i++) acc[i][j] += av[i];
    }
  }

  if (!transposed) {  // out[b][pos][r]
    #pragma unroll
    for (int i = 0; i < 4; i++) {
      Pk8 pk;
      #pragma unroll
      for (int j = 0; j < 8; j++) pk.u[j] = f2h(acc[i][j]);
      *(uintx4*)(outp + (size_t)(b * HW + pos0 + pt * 4 + i) * RP + rt * 8) = pk.v;
    }
  } else {            // out[b][r][pos]
    #pragma unroll
    for (int j = 0; j < 8; j++) {
      Pk4 pk;
      #pragma unroll
      for (int i = 0; i < 4; i++) pk.u[i] = f2h(acc[i][j]);
      *(uintx2*)(outp + (size_t)(b * RP + rt * 8 + j) * HW + pos0 + pt * 4) = pk.v;
    }
  }
}

// ---------------------------------------------------------------------------
// Flash attention partials (split-K=2) + soft-argmax accumulators.
// theta[b][q][r], phiT[b][k][r], gT[b][v][k] (all fp16). Block: (b, 64 q,
// split of 2048 keys), 4 waves x 16 q. 32 K-tiles of 64 keys, double-buffered
// LDS, 1-iter register prefetch. mfma_f32_16x16x32_f16 (layouts m89/m91).
// Emits unnormalized accO (fp16) and m/l/aC (fp32) per query.
// ---------------------------------------------------------------------------
__global__ __launch_bounds__(256) void ra_flash(
    const u16* __restrict__ theta, const u16* __restrict__ phiT,
    const u16* __restrict__ gT, u16* __restrict__ pO,
    float* __restrict__ mla)
{
  // phi tile: [rchunk8 cb(16)][k(64)][16B], cb stride 65 uint4
  __shared__ uintx4 phi_lds[2][16 * 65];
  // g tile:  [kchunk8 kcb(8)][v(128)][16B], kcb stride 129 uint4
  __shared__ uintx4 g_lds[2][8 * 129];
  // P round-trip, per-wave: [q(16)][k(64)] fp16, row stride 76 u16
  // (76 u16 = 38 dwords = 6 mod 32 -> quad qrow-diffs {4,8,12} land on
  // banks {24,16,8}: no cross-quad ds_write collisions)
  __shared__ u16 P_lds[4][16 * 76];

  const int tid  = threadIdx.x;
  const int bx   = blockIdx.x;
  const int b    = bx >> 7;
  const int rem  = bx & 127;
  const int q0   = (rem >> 1) * 64;
  const int split= rem & 1;
  const int kbase= split * 2048;
  const int wv   = tid >> 6;
  const int lane = tid & 63;
  const int ln16 = lane & 15;
  const int quad = lane >> 4;

  // theta A-fragments (held all kernel): 4 chunks of r (K=32 each)
  uintx4 aq[4];
  {
    const uintx4* tr = (const uintx4*)(theta + (size_t)(b * HW + q0 + wv * 16 + ln16) * RP);
    #pragma unroll
    for (int c = 0; c < 4; c++) aq[c] = tr[c * 4 + quad];
  }

  floatx4 accO[8];
  #pragma unroll
  for (int v = 0; v < 8; v++) accO[v] = (floatx4)0.0f;
  float m_r[4], l_r[4], aC[4];
  #pragma unroll
  for (int r = 0; r < 4; r++) { m_r[r] = -3.0e38f; l_r[r] = 0.f; aC[r] = 0.f; }

  const int sk  = tid >> 4, scb = tid & 15;  // phi staging
  const int gv_ = tid >> 3, gcb = tid & 7;   // g staging

  uintx4 sp[4], sg[4];
  #pragma unroll
  for (int i = 0; i < 4; i++) {
    sp[i] = *(const uintx4*)(phiT + (size_t)(b * HW + kbase + i * 16 + sk) * RP + scb * 8);
    sg[i] = *(const uintx4*)(gT + (size_t)(b * RP + i * 32 + gv_) * HW + kbase + gcb * 8);
  }

  #pragma unroll 1
  for (int j = 0; j < 32; j++) {
    const int buf = j & 1;
    #pragma unroll
    for (int i = 0; i < 4; i++) {
      phi_lds[buf][scb * 65 + i * 16 + sk] = sp[i];
      g_lds[buf][gcb * 129 + i * 32 + gv_] = sg[i];
    }
    if (j < 31) {  // prefetch next tile into regs
      const int k0n = kbase + (j + 1) * 64;
      #pragma unroll
      for (int i = 0; i < 4; i++) {
        sp[i] = *(const uintx4*)(phiT + (size_t)(b * HW + k0n + i * 16 + sk) * RP + scb * 8);
        sg[i] = *(const uintx4*)(gT + (size_t)(b * RP + i * 32 + gv_) * HW + k0n + gcb * 8);
      }
    }
    __syncthreads();  // barrier A: tiles visible; orders P read(j-1) vs write(j)

    // S[16q x 64k] = theta . phiT
    floatx4 sf[4];
    #pragma unroll
    for (int s = 0; s < 4; s++) sf[s] = (floatx4)0.0f;
    #pragma unroll
    for (int c = 0; c < 4; c++) {
      half8 a = as_h8(aq[c]);
      #pragma unroll
      for (int s = 0; s < 4; s++) {
        uintx4 bp = phi_lds[buf][(c * 4 + quad) * 65 + s * 16 + ln16];
        sf[s] = __builtin_amdgcn_mfma_f32_16x16x32_f16(a, as_h8(bp), sf[s], 0, 0, 0);
      }
    }

    // online softmax + col accumulation; write P (fp16) for A-operand re-read
    const float colbase = (float)((j * 64) & 127) + (float)ln16;  // kbase%128==0
    #pragma unroll
    for (int r = 0; r < 4; r++) {
      float mx = fmaxf(fmaxf(sf[0][r], sf[1][r]), fmaxf(sf[2][r], sf[3][r]));
      mx = fmaxf(mx, __shfl_xor(mx, 1));
      mx = fmaxf(mx, __shfl_xor(mx, 2));
      mx = fmaxf(mx, __shfl_xor(mx, 4));
      mx = fmaxf(mx, __shfl_xor(mx, 8));
      const float mnew  = fmaxf(m_r[r], mx);
      const float alpha = __expf(m_r[r] - mnew);
      m_r[r] = mnew;
      float p0 = __expf(sf[0][r] - mnew);
      float p1 = __expf(sf[1][r] - mnew);
      float p2 = __expf(sf[2][r] - mnew);
      float p3 = __expf(sf[3][r] - mnew);
      float ps = p0 + p1 + p2 + p3;
      float pc = p0 * colbase + p1 * (colbase + 16.f) + p2 * (colbase + 32.f) + p3 * (colbase + 48.f);
      ps += __shfl_xor(ps, 1); ps += __shfl_xor(ps, 2);
      ps += __shfl_xor(ps, 4); ps += __shfl_xor(ps, 8);
      pc += __shfl_xor(pc, 1); pc += __shfl_xor(pc, 2);
      pc += __shfl_xor(pc, 4); pc += __shfl_xor(pc, 8);
      l_r[r] = l_r[r] * alpha + ps;
      aC[r]  = aC[r]  * alpha + pc;
      #pragma unroll
      for (int v = 0; v < 8; v++) accO[v][r] *= alpha;
      const int qrow = quad * 4 + r;
      P_lds[wv][qrow * 76 +      ln16] = f2h(p0);
      P_lds[wv][qrow * 76 + 16 + ln16] = f2h(p1);
      P_lds[wv][qrow * 76 + 32 + ln16] = f2h(p2);
      P_lds[wv][qrow * 76 + 48 + ln16] = f2h(p3);
    }
    __syncthreads();  // barrier B: P C-layout -> A-layout visible

    half8 pa0 = as_h8(*(const uintx4*)&P_lds[wv][ln16 * 76 + quad * 8]);
    half8 pa1 = as_h8(*(const uintx4*)&P_lds[wv][ln16 * 76 + 32 + quad * 8]);
    #pragma unroll
    for (int v = 0; v < 8; v++) {
      uintx4 bg0 = g_lds[buf][quad * 129 + v * 16 + ln16];
      uintx4 bg1 = g_lds[buf][(4 + quad) * 129 + v * 16 + ln16];
      accO[v] = __builtin_amdgcn_mfma_f32_16x16x32_f16(pa0, as_h8(bg0), accO[v], 0, 0, 0);
      accO[v] = __builtin_amdgcn_mfma_f32_16x16x32_f16(pa1, as_h8(bg1), accO[v], 0, 0, 0);
    }
  }

  // epilogue: unnormalized partials
  #pragma unroll
  for (int r = 0; r < 4; r++) {
    const int q = q0 + wv * 16 + quad * 4 + r;
    const size_t p = (size_t)split * 16384 + b * HW + q;
    u16* orow = pO + p * RP;
    #pragma unroll
    for (int v = 0; v < 8; v++) orow[v * 16 + ln16] = f2h(accO[v][r]);
    if (ln16 == 0) {
      float* m4 = mla + p * 4;
      m4[0] = m_r[r]; m4[1] = l_r[r]; m4[2] = aC[r];
    }
  }
}

// ---------------------------------------------------------------------------
// Combine split-K partials: after (bf16) + index (fp32).
// Block 256 = 2 queries x 128 v. p = b*HW+q flat in [0,16384).
// ---------------------------------------------------------------------------
__global__ __launch_bounds__(256) void ra_combine(
    const u16* __restrict__ pO, const float* __restrict__ mla,
    u16* __restrict__ after, float* __restrict__ index_out)
{
  const int t = threadIdx.x;
  const int p = blockIdx.x * 2 + (t >> 7);
  const int v = t & 127;
  const floatx4 A = *(const floatx4*)(mla + (size_t)p * 4);             // m0,l0,c0
  const floatx4 Bv = *(const floatx4*)(mla + (size_t)(16384 + p) * 4);  // m1,l1,c1
  const float M  = fmaxf(A[0], Bv[0]);
  const float w0 = __expf(A[0] - M), w1 = __expf(Bv[0] - M);
  const float inv = 1.0f / (w0 * A[1] + w1 * Bv[1]);
  const float a0 = h2f(pO[(size_t)p * RP + v]);
  const float a1 = h2f(pO[(size_t)(16384 + p) * RP + v]);
  after[(size_t)p * RP + v] = f2bf((w0 * a0 + w1 * a1) * inv);
  if (v == 0) index_out[p] = (float)(p & 127) - (w0 * A[2] + w1 * Bv[2]) * inv;
}

// ---------------------------------------------------------------------------
// Up-projection: y[b,co,pos] = sum_r after[b,pos,r]*up_w[co,r] + up_b[co] (bf16 out)
// ---------------------------------------------------------------------------
__global__ __launch_bounds__(256) void ra_up(
    const u16* __restrict__ after, const float* __restrict__ w,
    const float* __restrict__ bias, u16* __restrict__ y)
{
  __shared__ float x_lds[32][68];   // [r][pos]
  __shared__ float w_lds[32][132];  // [r][co]
  const int tid  = threadIdx.x;
  const int bx   = blockIdx.x;
  const int b    = bx >> 7;
  const int pos0 = ((bx >> 1) & 63) * 64;
  const int hc   = bx & 1;
  const int rt = tid & 15, pt = tid >> 4;

  float acc[4][8];
  #pragma unroll
  for (int i = 0; i < 4; i++)
    #pragma unroll
    for (int j = 0; j < 8; j++) acc[i][j] = 0.f;

  const int apos = tid >> 2, ars = (tid & 3) * 8;
  const int wr_ = tid >> 1, wc_ = (tid & 1) * 16;

  for (int cc = 0; cc < 4; ++cc) {
    {
      const u16* ar = after + (size_t)(b * HW + pos0 + apos) * RP + cc * 32 + ars;
      uintx4 raw = *(const uintx4*)ar;
      #pragma unroll
      for (int k = 0; k < 4; k++) {
        u32 wd = raw[k];
        x_lds[ars + 2 * k][apos]     = bf2f((u16)(wd & 0xffffu));
        x_lds[ars + 2 * k + 1][apos] = bf2f((u16)(wd >> 16));
      }
    }
    {
      const float* wp = w + (size_t)(hc * 128 + wr_) * RP + cc * 32 + wc_;
      #pragma unroll
      for (int jj = 0; jj < 16; jj++) w_lds[wc_ + jj][wr_] = wp[jj];
    }
    __syncthreads();
    #pragma unroll 8
    for (int c = 0; c < 32; c++) {
      floatx4 xv = *(const floatx4*)&x_lds[c][pt * 4];
      floatx4 w0 = *(const floatx4*)&w_lds[c][rt * 8];
      floatx4 w1 = *(const floatx4*)&w_lds[c][rt * 8 + 4];
      #pragma unroll
      for (int i = 0; i < 4; i++) {
        acc[i][0] += xv[i] * w0[0]; acc[i][1] += xv[i] * w0[1];
        acc[i][2] += xv[i] * w0[2]; acc[i][3] += xv[i] * w0[3];
        acc[i][4] += xv[i] * w1[0]; acc[i][5] += xv[i] * w1[1];
        acc[i][6] += xv[i] * w1[2]; acc[i][7] += xv[i] * w1[3];
      }
    }
    __syncthreads();
  }

  #pragma unroll
  for (int j = 0; j < 8; j++) {
    const int co = hc * 128 + rt * 8 + j;
    const float bs = bias[co];
    Pk4 pk;
    #pragma unroll
    for (int i = 0; i < 4; i++) pk.u[i] = f2bf(acc[i][j] + bs);
    *(uintx2*)(y + (size_t)(b * CB + co) * HW + pos0 + pt * 4) = pk.v;
  }
}

// ---------------------------------------------------------------------------
// Per-channel batch stats over (B, HW): mean and rstd.
// ---------------------------------------------------------------------------
__global__ __launch_bounds__(256) void ra_stats(const u16* __restrict__ y,
                                                float* __restrict__ stats)
{
  const int c = blockIdx.x;
  const int tid = threadIdx.x;
  float s = 0.f, sq = 0.f;
  for (int b = 0; b < 4; b++) {
    const uintx4* row = (const uintx4*)(y + (size_t)(b * CB + c) * HW);
    #pragma unroll
    for (int t = 0; t < 2; t++) {
      uintx4 rv = row[tid + t * 256];
      #pragma unroll
      for (int k = 0; k < 4; k++) {
        float a0 = bf2f((u16)(rv[k] & 0xffffu));
        float a1 = bf2f((u16)(rv[k] >> 16));
        s += a0 + a1; sq += a0 * a0 + a1 * a1;
      }
    }
  }
  #pragma unroll
  for (int m = 1; m < 64; m <<= 1) { s += __shfl_xor(s, m); sq += __shfl_xor(sq, m); }
  __shared__ float red[8];
  const int wv = tid >> 6;
  if ((tid & 63) == 0) { red[wv * 2] = s; red[wv * 2 + 1] = sq; }
  __syncthreads();
  if (tid == 0) {
    s  = red[0] + red[2] + red[4] + red[6];
    sq = red[1] + red[3] + red[5] + red[7];
    const float mean = s * (1.f / 16384.f);
    const float var  = sq * (1.f / 16384.f) - mean * mean;
    stats[2 * c]     = mean;
    stats[2 * c + 1] = rsqrtf(var + EPSF);
  }
}

// ---------------------------------------------------------------------------
// out = x + gamma*(y - mean)*rstd + beta  (elementwise, float4)
// ---------------------------------------------------------------------------
__global__ __launch_bounds__(256) void ra_fin(
    const float* __restrict__ x, const u16* __restrict__ y,
    const float* __restrict__ stats, const float* __restrict__ gamma,
    const float* __restrict__ beta, float* __restrict__ out)
{
  const size_t e = (size_t)blockIdx.x * 256 + threadIdx.x;  // float4 index
  const int c = (int)((e >> 10) & 255);
  const float mean = stats[2 * c], rstd = stats[2 * c + 1];
  const float ga = gamma[c], be = beta[c];
  floatx4 xv = ((const floatx4*)x)[e];
  uintx2 yv = ((const uintx2*)y)[e];
  float f0 = bf2f((u16)(yv[0] & 0xffffu));
  float f1 = bf2f((u16)(yv[0] >> 16));
  float f2 = bf2f((u16)(yv[1] & 0xffffu));
  float f3 = bf2f((u16)(yv[1] >> 16));
  floatx4 o;
  o[0] = xv[0] + ga * ((f0 - mean) * rstd) + be;
  o[1] = xv[1] + ga * ((f1 - mean) * rstd) + be;
  o[2] = xv[2] + ga * ((f2 - mean) * rstd) + be;
  o[3] = xv[3] + ga * ((f3 - mean) * rstd) + be;
  ((floatx4*)out)[e] = o;
}

// ---------------------------------------------------------------------------
extern "C" void kernel_launch(void* const* d_in, const int* in_sizes, int n_in,
                              void* d_out, int out_size, void* d_ws, size_t ws_size,
                              hipStream_t stream)
{
  const float* left    = (const float*)d_in[0];
  const float* right   = (const float*)d_in[1];
  const float* pre_l   = (const float*)d_in[2];
  const float* pre_r   = (const float*)d_in[3];
  const float* query_l = (const float*)d_in[4];
  const float* key_l   = (const float*)d_in[5];
  const float* query_r = (const float*)d_in[6];
  const float* key_r   = (const float*)d_in[7];
  const float* theta_w = (const float*)d_in[8];
  const float* theta_b = (const float*)d_in[9];
  const float* phi_w   = (const float*)d_in[10];
  const float* phi_b   = (const float*)d_in[11];
  const float* g_w     = (const float*)d_in[12];
  const float* g_b     = (const float*)d_in[13];
  const float* up_w    = (const float*)d_in[14];
  const float* up_b    = (const float*)d_in[15];
  const float* bn_g    = (const float*)d_in[16];
  const float* bn_b    = (const float*)d_in[17];
  float* out = (float*)d_out;

  char* ws = (char*)d_ws;
  const size_t SZ = (size_t)4 * HW * RP * 2;  // 4 MiB (fp16 [4][4096][128])
  u16* thetaL = (u16*)(ws);
  u16* phiTL  = (u16*)(ws + 1 * SZ);
  u16* gTL    = (u16*)(ws + 2 * SZ);
  u16* thetaR = (u16*)(ws + 3 * SZ);
  u16* phiTR  = (u16*)(ws + 4 * SZ);
  u16* gTR    = (u16*)(ws + 5 * SZ);
  u16* afterL = (u16*)(ws + 6 * SZ);
  u16* afterR = (u16*)(ws + 7 * SZ);
  u16* yL     = (u16*)(ws + 8 * SZ);    // 8 MiB
  u16* yR     = (u16*)(ws + 10 * SZ);   // 8 MiB
  float* stL  = (float*)(ws + 12 * SZ);
  float* stR  = (float*)(ws + 12 * SZ + 4096);
  u16*   pO   = (u16*)(ws + 12 * SZ + 16384);                       // 8 MiB (2 splits)
  float* mla  = (float*)(ws + 12 * SZ + 16384 + (size_t)8 * 1024 * 1024);  // 512 KiB

  dim3 blk(256);
  // side L: x_q=left, x_kv=right, query_l, key_r; side R mirrored.
  ra_proj<<<256, blk, 0, stream>>>(left,  theta_w, theta_b, query_l, pre_l,  thetaL, 257, 0);
  ra_proj<<<256, blk, 0, stream>>>(right, phi_w,   phi_b,   key_r,   nullptr, phiTL, 256, 0);
  ra_proj<<<256, blk, 0, stream>>>(right, g_w,     g_b,     nullptr, nullptr, gTL,   256, 1);
  ra_proj<<<256, blk, 0, stream>>>(right, theta_w, theta_b, query_r, pre_r,  thetaR, 257, 0);
  ra_proj<<<256, blk, 0, stream>>>(left,  phi_w,   phi_b,   key_l,   nullptr, phiTR, 256, 0);
  ra_proj<<<256, blk, 0, stream>>>(left,  g_w,     g_b,     nullptr, nullptr, gTR,   256, 1);

  ra_flash<<<512, blk, 0, stream>>>(thetaL, phiTL, gTL, pO, mla);
  ra_combine<<<8192, blk, 0, stream>>>(pO, mla, afterL, out + 8388608);
  ra_flash<<<512, blk, 0, stream>>>(thetaR, phiTR, gTR, pO, mla);
  ra_combine<<<8192, blk, 0, stream>>>(pO, mla, afterR, out + 8404992);

  ra_up<<<512, blk, 0, stream>>>(afterL, up_w, up_b, yL);
  ra_up<<<512, blk, 0, stream>>>(afterR, up_w, up_b, yR);

  ra_stats<<<256, blk, 0, stream>>>(yL, stL);
  ra_stats<<<256, blk, 0, stream>>>(yR, stR);

  ra_fin<<<4096, blk, 0, stream>>>(left,  yL, stL, bn_g, bn_b, out);
  ra_fin<<<4096, blk, 0, stream>>>(right, yR, stR, bn_g, bn_b, out + 4194304);

  (void)in_sizes; (void)n_in; (void)out_size; (void)ws_size;
}

// Round 4
// 469.678 us; speedup vs baseline: 1.3522x; 1.1719x over previous
//
#include <hip/hip_runtime.h>

// row_attention_maxindex on MI355X — R3: mega-proj (six projections in one
// 1536-block dispatch). R2 analysis: 6x ra_proj at 256 blocks = 1 block/CU
// each — barrier-lockstep latency-bound (~262 us total, 6x over fp32 VALU
// floor). One dispatch -> 6 blocks/CU co-residency overlaps staging/VALU/
// barrier phases across independent blocks. Flash (split-K=2) unchanged.

typedef unsigned short u16;
typedef unsigned int   u32;
typedef float        floatx4 __attribute__((ext_vector_type(4)));
typedef unsigned int uintx4  __attribute__((ext_vector_type(4)));
typedef unsigned int uintx2  __attribute__((ext_vector_type(2)));
typedef _Float16     half8   __attribute__((ext_vector_type(8)));

#define HW 4096
#define CB 256
#define RP 128
#define EPSF 1e-5f

static __device__ __forceinline__ u16 f2bf(float f) {
  u32 u = __float_as_uint(f);
  u32 r = u + 0x7FFFu + ((u >> 16) & 1u);   // RNE
  return (u16)(r >> 16);
}
static __device__ __forceinline__ float bf2f(u16 h) {
  return __uint_as_float(((u32)h) << 16);
}
static __device__ __forceinline__ u16 f2h(float f) {
  _Float16 h = (_Float16)f;                 // RNE
  return __builtin_bit_cast(u16, h);
}
static __device__ __forceinline__ float h2f(u16 h) {
  return (float)__builtin_bit_cast(_Float16, h);
}
static __device__ __forceinline__ half8 as_h8(uintx4 v) {
  return __builtin_bit_cast(half8, v);
}

union Pk8 { u16 u[8]; uintx4 v; };
union Pk4 { u16 u[4]; uintx2 v; };

// ---------------------------------------------------------------------------
// Mega-projection: 6 projections in one dispatch. blockIdx>>8 selects config.
// out[b,pos,r] (or transposed out[b,r,pos]) =
//   sum_c x[b,c,pos]*w[r,c] (+ pre[b,pos]/128 * w[r,256]) + bias[r] (+ addend[b,r,pos])
// Block: 64 pos x 128 r, 256 threads, thread = 4 pos x 8 r. Output fp16.
// ---------------------------------------------------------------------------
struct ProjCfg {
  const float* x; const float* w; const float* bias;
  const float* add; const float* pre; u16* out;
  int wstride; int transposed;
};
struct ProjCfg6 { ProjCfg c[6]; };

__global__ __launch_bounds__(256) void ra_proj6(ProjCfg6 cfg)
{
  __shared__ float x_lds[32][68];
  __shared__ float w_lds[32][132];
  const ProjCfg C = cfg.c[blockIdx.x >> 8];
  const float* __restrict__ x    = C.x;
  const float* __restrict__ w    = C.w;
  const float* __restrict__ bias = C.bias;
  const float* __restrict__ addend = C.add;
  const float* __restrict__ pre  = C.pre;
  u16* __restrict__ outp = C.out;
  const int wstride = C.wstride;

  const int tid  = threadIdx.x;
  const int inner= blockIdx.x & 255;
  const int b    = inner >> 6;
  const int pos0 = (inner & 63) * 64;
  const int rt = tid & 15, pt = tid >> 4;

  float acc[4][8];
  #pragma unroll
  for (int i = 0; i < 4; i++)
    #pragma unroll
    for (int j = 0; j < 8; j++) acc[i][j] = 0.f;

  const int xc = tid >> 3, xp = (tid & 7) * 8;        // x staging: c row, pos offset
  const int wr_ = tid >> 1, wc_ = (tid & 1) * 16;     // w staging

  for (int cc = 0; cc < 8; ++cc) {
    {
      const float* xr = x + ((size_t)(b * CB + cc * 32 + xc)) * HW + pos0 + xp;
      floatx4 a0 = *(const floatx4*)xr;
      floatx4 a1 = *(const floatx4*)(xr + 4);
      *(floatx4*)&x_lds[xc][xp]     = a0;
      *(floatx4*)&x_lds[xc][xp + 4] = a1;
    }
    {
      const float* wp = w + (size_t)wr_ * wstride + cc * 32 + wc_;
      #pragma unroll
      for (int jj = 0; jj < 16; jj++) w_lds[wc_ + jj][wr_] = wp[jj];
    }
    __syncthreads();
    #pragma unroll 8
    for (int c = 0; c < 32; c++) {
      floatx4 xv = *(const floatx4*)&x_lds[c][pt * 4];
      floatx4 w0 = *(const floatx4*)&w_lds[c][rt * 8];
      floatx4 w1 = *(const floatx4*)&w_lds[c][rt * 8 + 4];
      #pragma unroll
      for (int i = 0; i < 4; i++) {
        acc[i][0] += xv[i] * w0[0]; acc[i][1] += xv[i] * w0[1];
        acc[i][2] += xv[i] * w0[2]; acc[i][3] += xv[i] * w0[3];
        acc[i][4] += xv[i] * w1[0]; acc[i][5] += xv[i] * w1[1];
        acc[i][6] += xv[i] * w1[2]; acc[i][7] += xv[i] * w1[3];
      }
    }
    __syncthreads();
  }

  if (pre) {  // extra channel 256: pre/128 * w[r][256]
    float wcol[8];
    #pragma unroll
    for (int j = 0; j < 8; j++) wcol[j] = w[(size_t)(rt * 8 + j) * wstride + 256];
    #pragma unroll
    for (int i = 0; i < 4; i++) {
      float pv = pre[(size_t)b * HW + pos0 + pt * 4 + i] * (1.f / 128.f);
      #pragma unroll
      for (int j = 0; j < 8; j++) acc[i][j] += pv * wcol[j];
    }
  }
  #pragma unroll
  for (int j = 0; j < 8; j++) {
    float bs = bias[rt * 8 + j];
    #pragma unroll
    for (int i = 0; i < 4; i++) acc[i][j] += bs;
  }
  if (addend) {  // addend[b][r][pos]
    #pragma unroll
    for (int j = 0; j < 8; j++) {
      floatx4 av = *(const floatx4*)(addend + (size_t)(b * RP + rt * 8 + j) * HW + pos0 + pt * 4);
      #pragma unroll
      for (int i = 0; i < 4; i++) acc[i][j] += av[i];
    }
  }

  if (!C.transposed) {  // out[b][pos][r]
    #pragma unroll
    for (int i = 0; i < 4; i++) {
      Pk8 pk;
      #pragma unroll
      for (int j = 0; j < 8; j++) pk.u[j] = f2h(acc[i][j]);
      *(uintx4*)(outp + (size_t)(b * HW + pos0 + pt * 4 + i) * RP + rt * 8) = pk.v;
    }
  } else {            // out[b][r][pos]
    #pragma unroll
    for (int j = 0; j < 8; j++) {
      Pk4 pk;
      #pragma unroll
      for (int i = 0; i < 4; i++) pk.u[i] = f2h(acc[i][j]);
      *(uintx2*)(outp + (size_t)(b * RP + rt * 8 + j) * HW + pos0 + pt * 4) = pk.v;
    }
  }
}

// ---------------------------------------------------------------------------
// Flash attention partials (split-K=2) + soft-argmax accumulators.
// theta[b][q][r], phiT[b][k][r], gT[b][v][k] (all fp16). Block: (b, 64 q,
// split of 2048 keys), 4 waves x 16 q. 32 K-tiles of 64 keys, double-buffered
// LDS, 1-iter register prefetch. mfma_f32_16x16x32_f16 (layouts m89/m91).
// Emits unnormalized accO (fp16) and m/l/aC (fp32) per query.
// ---------------------------------------------------------------------------
__global__ __launch_bounds__(256) void ra_flash(
    const u16* __restrict__ theta, const u16* __restrict__ phiT,
    const u16* __restrict__ gT, u16* __restrict__ pO,
    float* __restrict__ mla)
{
  // phi tile: [rchunk8 cb(16)][k(64)][16B], cb stride 65 uint4
  __shared__ uintx4 phi_lds[2][16 * 65];
  // g tile:  [kchunk8 kcb(8)][v(128)][16B], kcb stride 129 uint4
  __shared__ uintx4 g_lds[2][8 * 129];
  // P round-trip, per-wave: [q(16)][k(64)] fp16, row stride 76 u16
  __shared__ u16 P_lds[4][16 * 76];

  const int tid  = threadIdx.x;
  const int bx   = blockIdx.x;
  const int b    = bx >> 7;
  const int rem  = bx & 127;
  const int q0   = (rem >> 1) * 64;
  const int split= rem & 1;
  const int kbase= split * 2048;
  const int wv   = tid >> 6;
  const int lane = tid & 63;
  const int ln16 = lane & 15;
  const int quad = lane >> 4;

  // theta A-fragments (held all kernel): 4 chunks of r (K=32 each)
  uintx4 aq[4];
  {
    const uintx4* tr = (const uintx4*)(theta + (size_t)(b * HW + q0 + wv * 16 + ln16) * RP);
    #pragma unroll
    for (int c = 0; c < 4; c++) aq[c] = tr[c * 4 + quad];
  }

  floatx4 accO[8];
  #pragma unroll
  for (int v = 0; v < 8; v++) accO[v] = (floatx4)0.0f;
  float m_r[4], l_r[4], aC[4];
  #pragma unroll
  for (int r = 0; r < 4; r++) { m_r[r] = -3.0e38f; l_r[r] = 0.f; aC[r] = 0.f; }

  const int sk  = tid >> 4, scb = tid & 15;  // phi staging
  const int gv_ = tid >> 3, gcb = tid & 7;   // g staging

  uintx4 sp[4], sg[4];
  #pragma unroll
  for (int i = 0; i < 4; i++) {
    sp[i] = *(const uintx4*)(phiT + (size_t)(b * HW + kbase + i * 16 + sk) * RP + scb * 8);
    sg[i] = *(const uintx4*)(gT + (size_t)(b * RP + i * 32 + gv_) * HW + kbase + gcb * 8);
  }

  #pragma unroll 1
  for (int j = 0; j < 32; j++) {
    const int buf = j & 1;
    #pragma unroll
    for (int i = 0; i < 4; i++) {
      phi_lds[buf][scb * 65 + i * 16 + sk] = sp[i];
      g_lds[buf][gcb * 129 + i * 32 + gv_] = sg[i];
    }
    if (j < 31) {  // prefetch next tile into regs
      const int k0n = kbase + (j + 1) * 64;
      #pragma unroll
      for (int i = 0; i < 4; i++) {
        sp[i] = *(const uintx4*)(phiT + (size_t)(b * HW + k0n + i * 16 + sk) * RP + scb * 8);
        sg[i] = *(const uintx4*)(gT + (size_t)(b * RP + i * 32 + gv_) * HW + k0n + gcb * 8);
      }
    }
    __syncthreads();  // barrier A: tiles visible; orders P read(j-1) vs write(j)

    // S[16q x 64k] = theta . phiT
    floatx4 sf[4];
    #pragma unroll
    for (int s = 0; s < 4; s++) sf[s] = (floatx4)0.0f;
    #pragma unroll
    for (int c = 0; c < 4; c++) {
      half8 a = as_h8(aq[c]);
      #pragma unroll
      for (int s = 0; s < 4; s++) {
        uintx4 bp = phi_lds[buf][(c * 4 + quad) * 65 + s * 16 + ln16];
        sf[s] = __builtin_amdgcn_mfma_f32_16x16x32_f16(a, as_h8(bp), sf[s], 0, 0, 0);
      }
    }

    // online softmax + col accumulation; write P (fp16) for A-operand re-read
    const float colbase = (float)((j * 64) & 127) + (float)ln16;  // kbase%128==0
    #pragma unroll
    for (int r = 0; r < 4; r++) {
      float mx = fmaxf(fmaxf(sf[0][r], sf[1][r]), fmaxf(sf[2][r], sf[3][r]));
      mx = fmaxf(mx, __shfl_xor(mx, 1));
      mx = fmaxf(mx, __shfl_xor(mx, 2));
      mx = fmaxf(mx, __shfl_xor(mx, 4));
      mx = fmaxf(mx, __shfl_xor(mx, 8));
      const float mnew  = fmaxf(m_r[r], mx);
      const float alpha = __expf(m_r[r] - mnew);
      m_r[r] = mnew;
      float p0 = __expf(sf[0][r] - mnew);
      float p1 = __expf(sf[1][r] - mnew);
      float p2 = __expf(sf[2][r] - mnew);
      float p3 = __expf(sf[3][r] - mnew);
      float ps = p0 + p1 + p2 + p3;
      float pc = p0 * colbase + p1 * (colbase + 16.f) + p2 * (colbase + 32.f) + p3 * (colbase + 48.f);
      ps += __shfl_xor(ps, 1); ps += __shfl_xor(ps, 2);
      ps += __shfl_xor(ps, 4); ps += __shfl_xor(ps, 8);
      pc += __shfl_xor(pc, 1); pc += __shfl_xor(pc, 2);
      pc += __shfl_xor(pc, 4); pc += __shfl_xor(pc, 8);
      l_r[r] = l_r[r] * alpha + ps;
      aC[r]  = aC[r]  * alpha + pc;
      #pragma unroll
      for (int v = 0; v < 8; v++) accO[v][r] *= alpha;
      const int qrow = quad * 4 + r;
      P_lds[wv][qrow * 76 +      ln16] = f2h(p0);
      P_lds[wv][qrow * 76 + 16 + ln16] = f2h(p1);
      P_lds[wv][qrow * 76 + 32 + ln16] = f2h(p2);
      P_lds[wv][qrow * 76 + 48 + ln16] = f2h(p3);
    }
    __syncthreads();  // barrier B: P C-layout -> A-layout visible

    half8 pa0 = as_h8(*(const uintx4*)&P_lds[wv][ln16 * 76 + quad * 8]);
    half8 pa1 = as_h8(*(const uintx4*)&P_lds[wv][ln16 * 76 + 32 + quad * 8]);
    #pragma unroll
    for (int v = 0; v < 8; v++) {
      uintx4 bg0 = g_lds[buf][quad * 129 + v * 16 + ln16];
      uintx4 bg1 = g_lds[buf][(4 + quad) * 129 + v * 16 + ln16];
      accO[v] = __builtin_amdgcn_mfma_f32_16x16x32_f16(pa0, as_h8(bg0), accO[v], 0, 0, 0);
      accO[v] = __builtin_amdgcn_mfma_f32_16x16x32_f16(pa1, as_h8(bg1), accO[v], 0, 0, 0);
    }
  }

  // epilogue: unnormalized partials
  #pragma unroll
  for (int r = 0; r < 4; r++) {
    const int q = q0 + wv * 16 + quad * 4 + r;
    const size_t p = (size_t)split * 16384 + b * HW + q;
    u16* orow = pO + p * RP;
    #pragma unroll
    for (int v = 0; v < 8; v++) orow[v * 16 + ln16] = f2h(accO[v][r]);
    if (ln16 == 0) {
      float* m4 = mla + p * 4;
      m4[0] = m_r[r]; m4[1] = l_r[r]; m4[2] = aC[r];
    }
  }
}

// ---------------------------------------------------------------------------
// Combine split-K partials: after (bf16) + index (fp32).
// Block 256 = 2 queries x 128 v. p = b*HW+q flat in [0,16384).
// ---------------------------------------------------------------------------
__global__ __launch_bounds__(256) void ra_combine(
    const u16* __restrict__ pO, const float* __restrict__ mla,
    u16* __restrict__ after, float* __restrict__ index_out)
{
  const int t = threadIdx.x;
  const int p = blockIdx.x * 2 + (t >> 7);
  const int v = t & 127;
  const floatx4 A = *(const floatx4*)(mla + (size_t)p * 4);             // m0,l0,c0
  const floatx4 Bv = *(const floatx4*)(mla + (size_t)(16384 + p) * 4);  // m1,l1,c1
  const float M  = fmaxf(A[0], Bv[0]);
  const float w0 = __expf(A[0] - M), w1 = __expf(Bv[0] - M);
  const float inv = 1.0f / (w0 * A[1] + w1 * Bv[1]);
  const float a0 = h2f(pO[(size_t)p * RP + v]);
  const float a1 = h2f(pO[(size_t)(16384 + p) * RP + v]);
  after[(size_t)p * RP + v] = f2bf((w0 * a0 + w1 * a1) * inv);
  if (v == 0) index_out[p] = (float)(p & 127) - (w0 * A[2] + w1 * Bv[2]) * inv;
}

// ---------------------------------------------------------------------------
// Up-projection: y[b,co,pos] = sum_r after[b,pos,r]*up_w[co,r] + up_b[co] (bf16 out)
// ---------------------------------------------------------------------------
__global__ __launch_bounds__(256) void ra_up(
    const u16* __restrict__ after, const float* __restrict__ w,
    const float* __restrict__ bias, u16* __restrict__ y)
{
  __shared__ float x_lds[32][68];   // [r][pos]
  __shared__ float w_lds[32][132];  // [r][co]
  const int tid  = threadIdx.x;
  const int bx   = blockIdx.x;
  const int b    = bx >> 7;
  const int pos0 = ((bx >> 1) & 63) * 64;
  const int hc   = bx & 1;
  const int rt = tid & 15, pt = tid >> 4;

  float acc[4][8];
  #pragma unroll
  for (int i = 0; i < 4; i++)
    #pragma unroll
    for (int j = 0; j < 8; j++) acc[i][j] = 0.f;

  const int apos = tid >> 2, ars = (tid & 3) * 8;
  const int wr_ = tid >> 1, wc_ = (tid & 1) * 16;

  for (int cc = 0; cc < 4; ++cc) {
    {
      const u16* ar = after + (size_t)(b * HW + pos0 + apos) * RP + cc * 32 + ars;
      uintx4 raw = *(const uintx4*)ar;
      #pragma unroll
      for (int k = 0; k < 4; k++) {
        u32 wd = raw[k];
        x_lds[ars + 2 * k][apos]     = bf2f((u16)(wd & 0xffffu));
        x_lds[ars + 2 * k + 1][apos] = bf2f((u16)(wd >> 16));
      }
    }
    {
      const float* wp = w + (size_t)(hc * 128 + wr_) * RP + cc * 32 + wc_;
      #pragma unroll
      for (int jj = 0; jj < 16; jj++) w_lds[wc_ + jj][wr_] = wp[jj];
    }
    __syncthreads();
    #pragma unroll 8
    for (int c = 0; c < 32; c++) {
      floatx4 xv = *(const floatx4*)&x_lds[c][pt * 4];
      floatx4 w0 = *(const floatx4*)&w_lds[c][rt * 8];
      floatx4 w1 = *(const floatx4*)&w_lds[c][rt * 8 + 4];
      #pragma unroll
      for (int i = 0; i < 4; i++) {
        acc[i][0] += xv[i] * w0[0]; acc[i][1] += xv[i] * w0[1];
        acc[i][2] += xv[i] * w0[2]; acc[i][3] += xv[i] * w0[3];
        acc[i][4] += xv[i] * w1[0]; acc[i][5] += xv[i] * w1[1];
        acc[i][6] += xv[i] * w1[2]; acc[i][7] += xv[i] * w1[3];
      }
    }
    __syncthreads();
  }

  #pragma unroll
  for (int j = 0; j < 8; j++) {
    const int co = hc * 128 + rt * 8 + j;
    const float bs = bias[co];
    Pk4 pk;
    #pragma unroll
    for (int i = 0; i < 4; i++) pk.u[i] = f2bf(acc[i][j] + bs);
    *(uintx2*)(y + (size_t)(b * CB + co) * HW + pos0 + pt * 4) = pk.v;
  }
}

// ---------------------------------------------------------------------------
// Per-channel batch stats over (B, HW): mean and rstd.
// ---------------------------------------------------------------------------
__global__ __launch_bounds__(256) void ra_stats(const u16* __restrict__ y,
                                                float* __restrict__ stats)
{
  const int c = blockIdx.x;
  const int tid = threadIdx.x;
  float s = 0.f, sq = 0.f;
  for (int b = 0; b < 4; b++) {
    const uintx4* row = (const uintx4*)(y + (size_t)(b * CB + c) * HW);
    #pragma unroll
    for (int t = 0; t < 2; t++) {
      uintx4 rv = row[tid + t * 256];
      #pragma unroll
      for (int k = 0; k < 4; k++) {
        float a0 = bf2f((u16)(rv[k] & 0xffffu));
        float a1 = bf2f((u16)(rv[k] >> 16));
        s += a0 + a1; sq += a0 * a0 + a1 * a1;
      }
    }
  }
  #pragma unroll
  for (int m = 1; m < 64; m <<= 1) { s += __shfl_xor(s, m); sq += __shfl_xor(sq, m); }
  __shared__ float red[8];
  const int wv = tid >> 6;
  if ((tid & 63) == 0) { red[wv * 2] = s; red[wv * 2 + 1] = sq; }
  __syncthreads();
  if (tid == 0) {
    s  = red[0] + red[2] + red[4] + red[6];
    sq = red[1] + red[3] + red[5] + red[7];
    const float mean = s * (1.f / 16384.f);
    const float var  = sq * (1.f / 16384.f) - mean * mean;
    stats[2 * c]     = mean;
    stats[2 * c + 1] = rsqrtf(var + EPSF);
  }
}

// ---------------------------------------------------------------------------
// out = x + gamma*(y - mean)*rstd + beta  (elementwise, float4)
// ---------------------------------------------------------------------------
__global__ __launch_bounds__(256) void ra_fin(
    const float* __restrict__ x, const u16* __restrict__ y,
    const float* __restrict__ stats, const float* __restrict__ gamma,
    const float* __restrict__ beta, float* __restrict__ out)
{
  const size_t e = (size_t)blockIdx.x * 256 + threadIdx.x;  // float4 index
  const int c = (int)((e >> 10) & 255);
  const float mean = stats[2 * c], rstd = stats[2 * c + 1];
  const float ga = gamma[c], be = beta[c];
  floatx4 xv = ((const floatx4*)x)[e];
  uintx2 yv = ((const uintx2*)y)[e];
  float f0 = bf2f((u16)(yv[0] & 0xffffu));
  float f1 = bf2f((u16)(yv[0] >> 16));
  float f2 = bf2f((u16)(yv[1] & 0xffffu));
  float f3 = bf2f((u16)(yv[1] >> 16));
  floatx4 o;
  o[0] = xv[0] + ga * ((f0 - mean) * rstd) + be;
  o[1] = xv[1] + ga * ((f1 - mean) * rstd) + be;
  o[2] = xv[2] + ga * ((f2 - mean) * rstd) + be;
  o[3] = xv[3] + ga * ((f3 - mean) * rstd) + be;
  ((floatx4*)out)[e] = o;
}

// ---------------------------------------------------------------------------
extern "C" void kernel_launch(void* const* d_in, const int* in_sizes, int n_in,
                              void* d_out, int out_size, void* d_ws, size_t ws_size,
                              hipStream_t stream)
{
  const float* left    = (const float*)d_in[0];
  const float* right   = (const float*)d_in[1];
  const float* pre_l   = (const float*)d_in[2];
  const float* pre_r   = (const float*)d_in[3];
  const float* query_l = (const float*)d_in[4];
  const float* key_l   = (const float*)d_in[5];
  const float* query_r = (const float*)d_in[6];
  const float* key_r   = (const float*)d_in[7];
  const float* theta_w = (const float*)d_in[8];
  const float* theta_b = (const float*)d_in[9];
  const float* phi_w   = (const float*)d_in[10];
  const float* phi_b   = (const float*)d_in[11];
  const float* g_w     = (const float*)d_in[12];
  const float* g_b     = (const float*)d_in[13];
  const float* up_w    = (const float*)d_in[14];
  const float* up_b    = (const float*)d_in[15];
  const float* bn_g    = (const float*)d_in[16];
  const float* bn_b    = (const float*)d_in[17];
  float* out = (float*)d_out;

  char* ws = (char*)d_ws;
  const size_t SZ = (size_t)4 * HW * RP * 2;  // 4 MiB (fp16 [4][4096][128])
  u16* thetaL = (u16*)(ws);
  u16* phiTL  = (u16*)(ws + 1 * SZ);
  u16* gTL    = (u16*)(ws + 2 * SZ);
  u16* thetaR = (u16*)(ws + 3 * SZ);
  u16* phiTR  = (u16*)(ws + 4 * SZ);
  u16* gTR    = (u16*)(ws + 5 * SZ);
  u16* afterL = (u16*)(ws + 6 * SZ);
  u16* afterR = (u16*)(ws + 7 * SZ);
  u16* yL     = (u16*)(ws + 8 * SZ);    // 8 MiB
  u16* yR     = (u16*)(ws + 10 * SZ);   // 8 MiB
  float* stL  = (float*)(ws + 12 * SZ);
  float* stR  = (float*)(ws + 12 * SZ + 4096);
  u16*   pO   = (u16*)(ws + 12 * SZ + 16384);                       // 8 MiB (2 splits)
  float* mla  = (float*)(ws + 12 * SZ + 16384 + (size_t)8 * 1024 * 1024);  // 512 KiB

  dim3 blk(256);
  // side L: x_q=left, x_kv=right, query_l, key_r; side R mirrored.
  ProjCfg6 pc;
  pc.c[0] = { left,  theta_w, theta_b, query_l, pre_l,   thetaL, 257, 0 };
  pc.c[1] = { right, phi_w,   phi_b,   key_r,   nullptr, phiTL,  256, 0 };
  pc.c[2] = { right, g_w,     g_b,     nullptr, nullptr, gTL,    256, 1 };
  pc.c[3] = { right, theta_w, theta_b, query_r, pre_r,   thetaR, 257, 0 };
  pc.c[4] = { left,  phi_w,   phi_b,   key_l,   nullptr, phiTR,  256, 0 };
  pc.c[5] = { left,  g_w,     g_b,     nullptr, nullptr, gTR,    256, 1 };
  ra_proj6<<<1536, blk, 0, stream>>>(pc);

  ra_flash<<<512, blk, 0, stream>>>(thetaL, phiTL, gTL, pO, mla);
  ra_combine<<<8192, blk, 0, stream>>>(pO, mla, afterL, out + 8388608);
  ra_flash<<<512, blk, 0, stream>>>(thetaR, phiTR, gTR, pO, mla);
  ra_combine<<<8192, blk, 0, stream>>>(pO, mla, afterR, out + 8404992);

  ra_up<<<512, blk, 0, stream>>>(afterL, up_w, up_b, yL);
  ra_up<<<512, blk, 0, stream>>>(afterR, up_w, up_b, yR);

  ra_stats<<<256, blk, 0, stream>>>(yL, stL);
  ra_stats<<<256, blk, 0, stream>>>(yR, stR);

  ra_fin<<<4096, blk, 0, stream>>>(left,  yL, stL, bn_g, bn_b, out);
  ra_fin<<<4096, blk, 0, stream>>>(right, yR, stR, bn_g, bn_b, out + 4194304);

  (void)in_sizes; (void)n_in; (void)out_size; (void)ws_size;
}